// Round 11
// baseline (110.501 us; speedup 1.0000x reference)
//
#include <hip/hip_runtime.h>
#include <hip/hip_bf16.h>

typedef unsigned short u16;
typedef __bf16 bf16x8 __attribute__((ext_vector_type(8)));
typedef _Float16 f16x8 __attribute__((ext_vector_type(8)));
typedef float f32x4 __attribute__((ext_vector_type(4)));

#define DEVINL __device__ __forceinline__

static constexpr int Bc = 8, Tc = 2048;

DEVINL u16 f2bf(float f) {
  unsigned u = __builtin_bit_cast(unsigned, f);
  unsigned r = u + 0x7fffu + ((u >> 16) & 1u);   // RNE
  return (u16)(r >> 16);
}
DEVINL float bf2f(u16 h) {
  unsigned u = ((unsigned)h) << 16;
  return __builtin_bit_cast(float, u);
}

// swizzled LDS read of 8 contiguous 16-bit elems from a [R][64] tile.
DEVINL bf16x8 lds_ld8(const u16* p, int row, int col) {
  return *(const bf16x8*)&p[row * 64 + (col ^ ((row & 7) << 3))];
}
DEVINL f16x8 lds_ld8h(const u16* p, int row, int col) {
  return *(const f16x8*)&p[row * 64 + (col ^ ((row & 7) << 3))];
}

// ---------------------------------------------------------------------------
// Kernel 0: pre-swizzled wt_s[ch][c][kc'] = f16(W_{c/64}[ch*64 + (kc' ^
// ((c&7)<<3))][c%64]).  Linear global order == desired LDS image, so
// global_load_lds (linear DMA) lands the swizzle for conflict-free b128 reads.
// NOTE: chunk stride 12288 is NOT a power of two -> / and % (R9 bug).
// ---------------------------------------------------------------------------
__global__ __launch_bounds__(256) void build_wt(const float* __restrict__ Wk,
                                                const float* __restrict__ Wq,
                                                const float* __restrict__ Wv,
                                                u16* __restrict__ wt_s) {
  int idx = blockIdx.x * 256 + threadIdx.x;      // 16*192*64 = 196608
  int ch = idx / 12288;
  int rem = idx - ch * 12288;
  int c = rem >> 6, kc = rem & 63;
  int k = ch * 64 + (kc ^ ((c & 7) << 3));
  const float* W = (c < 64) ? Wk : (c < 128 ? Wq : Wv);
  _Float16 h = (_Float16)W[k * 64 + (c & 63)];
  wt_s[idx] = __builtin_bit_cast(u16, h);
}

// ---------------------------------------------------------------------------
// Kernel 1: fused QKV projection, f16-single, BOTH operands LDS-staged.
// (unchanged from R10-measured version)
// ---------------------------------------------------------------------------
__global__ __launch_bounds__(256, 2) void proj_kernel(const float* __restrict__ x,
                                                      const u16* __restrict__ wt_s,
                                                      u16* __restrict__ kb_h, u16* __restrict__ kb_l,
                                                      u16* __restrict__ qb_h, u16* __restrict__ qb_l,
                                                      u16* __restrict__ vt) {
  __shared__ u16 wl[2][192 * 64];        // 48KB  wt chunk dbuf (pre-swizzled)
  __shared__ u16 xl[2][32 * 64];         // 8KB   x chunk dbuf (swizzled)
  const int t = threadIdx.x;
  const int w = t >> 6, lane = t & 63;
  const int l16 = lane & 15, lhi = lane >> 4;
  const int rb = blockIdx.x * 32;
  const int cb = w * 48;
  const int sr = t >> 3, sc = (t & 7) * 8;
  const f32x4* xrow = (const f32x4*)(x + (size_t)(rb + sr) * 1024 + sc);

  f32x4 acc[2][3];
#pragma unroll
  for (int a = 0; a < 2; ++a)
#pragma unroll
    for (int c = 0; c < 3; ++c) acc[a][c] = (f32x4){0.f, 0.f, 0.f, 0.f};

#define STAGE_WT(S, CH)                                                        \
  {                                                                            \
    const u16* src = wt_s + (size_t)(CH) * 12288 + t * 8;                      \
    u16* dst = &wl[S][t * 8];                                                  \
    _Pragma("unroll") for (int i = 0; i < 6; ++i)                              \
      __builtin_amdgcn_global_load_lds(                                        \
          (const __attribute__((address_space(1))) unsigned int*)(src + i * 2048), \
          (__attribute__((address_space(3))) unsigned int*)(dst + i * 2048),   \
          16, 0, 0);                                                           \
  }

#define CVT_STORE(S, F0, F1)                                                   \
  {                                                                            \
    union { _Float16 h[8]; uint4 v; } p_;                                      \
    _Pragma("unroll") for (int j = 0; j < 4; ++j) {                            \
      p_.h[j] = (_Float16)(F0)[j];                                             \
      p_.h[4 + j] = (_Float16)(F1)[j];                                         \
    }                                                                          \
    *(uint4*)&xl[S][sr * 64 + (sc ^ ((sr & 7) << 3))] = p_.v;                  \
  }

#define COMPUTE(S)                                                             \
  _Pragma("unroll") for (int kk = 0; kk < 2; ++kk) {                           \
    f16x8 a0 = lds_ld8h(xl[S], l16, kk * 32 + lhi * 8);                        \
    f16x8 a1 = lds_ld8h(xl[S], 16 + l16, kk * 32 + lhi * 8);                   \
    _Pragma("unroll") for (int tc = 0; tc < 3; ++tc) {                         \
      int c_ = cb + tc * 16 + l16;                                             \
      f16x8 bf = *(const f16x8*)&wl[S][c_ * 64 + ((kk * 32 + lhi * 8) ^ ((c_ & 7) << 3))]; \
      acc[0][tc] = __builtin_amdgcn_mfma_f32_16x16x32_f16(a0, bf, acc[0][tc], 0, 0, 0); \
      acc[1][tc] = __builtin_amdgcn_mfma_f32_16x16x32_f16(a1, bf, acc[1][tc], 0, 0, 0); \
    }                                                                          \
  }

  STAGE_WT(0, 0);
  {
    f32x4 A0 = __builtin_nontemporal_load(xrow);
    f32x4 A1 = __builtin_nontemporal_load(xrow + 1);
    CVT_STORE(0, A0, A1);
  }
  __syncthreads();

#pragma unroll 2
  for (int ch = 0; ch < 16; ++ch) {
    const int cur = ch & 1, nxt = cur ^ 1;
    f32x4 A0, A1;
    if (ch + 1 < 16) {
      STAGE_WT(nxt, ch + 1);
      A0 = __builtin_nontemporal_load(xrow + (ch + 1) * 16);
      A1 = __builtin_nontemporal_load(xrow + (ch + 1) * 16 + 1);
    }
    COMPUTE(cur);
    if (ch + 1 < 16) {
      CVT_STORE(nxt, A0, A1);
      __syncthreads();
    }
  }
#undef STAGE_WT
#undef CVT_STORE
#undef COMPUTE

#pragma unroll
  for (int ri = 0; ri < 2; ++ri) {
#pragma unroll
    for (int tc = 0; tc < 3; ++tc) {
      int gc = cb + tc * 16 + l16;
      int cc = gc & 63;
      int row = rb + ri * 16 + lhi * 4;
#pragma unroll
      for (int i = 0; i < 4; ++i) {
        float f = acc[ri][tc][i];
        int r = row + i;
        u16 h = f2bf(f);
        if (gc < 64) {
          size_t off = (size_t)r * 64 + cc;
          kb_h[off] = h; kb_l[off] = f2bf(f - bf2f(h));
        } else if (gc < 128) {
          size_t off = (size_t)r * 64 + cc;
          qb_h[off] = h; qb_l[off] = f2bf(f - bf2f(h));
        } else {
          int bb = r >> 11, tp = r & 2047;
          vt[((size_t)bb * 64 + cc) * 2048 + tp] = h;
        }
      }
    }
  }
}

// ---------------------------------------------------------------------------
// Kernel 2: causal flash attention, barrier-free, KV-chunk 256.
// 288 units/batch x 8 = 2304 blocks x 1 wave (2.25 waves/SIMD vs 1.25 at
// chunk 512). ONLY the chunking changes vs R10: V-loads keep the proven
// before-softmax placement (R7's regression was this confound).
// Unit map: 224 full units (nt=4) first, desc j per c; 64 diag units last.
// ---------------------------------------------------------------------------
__global__ __launch_bounds__(64, 2) void attn_kernel(const u16* __restrict__ qb_h,
                                                     const u16* __restrict__ qb_l,
                                                     const u16* __restrict__ kb_h,
                                                     const u16* __restrict__ kb_l,
                                                     const u16* __restrict__ vt,
                                                     float* __restrict__ po,
                                                     float* __restrict__ pml) {
  __shared__ u16 p_l[2][1024];           // per-rowset P tile (16x64, swizzled)

  const int t = threadIdx.x;             // one wave
  const int l16 = t & 15, lhi = t >> 4;
  const int u = blockIdx.x >> 3, b = blockIdx.x & 7;

  int c, j;
  if (u < 224) {                         // full units: c in 0..6, 56-8c each
    int rem = u; c = 0;
    while (rem >= 56 - 8 * c) { rem -= 56 - 8 * c; ++c; }
    j = 63 - rem;
  } else {                               // edge (diagonal) units
    int e = u - 224; c = e >> 3; j = 8 * c + 7 - (e & 7);
  }

  const int kv0 = c << 8;
  const int prefix = j * 32 + 32;
  const int kv_end = (prefix < kv0 + 256) ? prefix : (kv0 + 256);
  const int nt = (kv_end - kv0 + 63) >> 6;
  const bool diag = (kv_end == prefix);

  const size_t qrow = (size_t)b * 2048 + j * 32;

  // Q fragments straight from global: lane l16 = q row, 16B contiguous cols
  bf16x8 aqh[2][2], aql[2][2];           // [rowset][kk]
#pragma unroll
  for (int rs = 0; rs < 2; ++rs)
#pragma unroll
    for (int kk = 0; kk < 2; ++kk) {
      size_t qo = (qrow + rs * 16 + l16) * 64 + kk * 32 + lhi * 8;
      aqh[rs][kk] = *(const bf16x8*)(qb_h + qo);
      aql[rs][kk] = *(const bf16x8*)(qb_l + qo);
    }

  f32x4 o[2][4];
  float m_r[2][4], l_r[2][4];
#pragma unroll
  for (int rs = 0; rs < 2; ++rs)
#pragma unroll
    for (int i = 0; i < 4; ++i) {
      o[rs][i] = (f32x4){0.f, 0.f, 0.f, 0.f};
      m_r[rs][i] = -3.0e38f; l_r[rs][i] = 0.f;
    }

  for (int tk = 0; tk < nt; ++tk) {
    const int kvb = kv0 + tk * 64;
    const size_t kbase = ((size_t)b * 2048 + kvb) * 64;

    // S = Q K^T: K frags loaded per-t4 (transient regs)
    f32x4 sa[2][4];
#pragma unroll
    for (int t4 = 0; t4 < 4; ++t4) {
      size_t kr = kbase + (size_t)(t4 * 16 + l16) * 64 + lhi * 8;
      bf16x8 kh0 = *(const bf16x8*)(kb_h + kr);
      bf16x8 kh1 = *(const bf16x8*)(kb_h + kr + 32);
      bf16x8 kl0 = *(const bf16x8*)(kb_l + kr);
      bf16x8 kl1 = *(const bf16x8*)(kb_l + kr + 32);
#pragma unroll
      for (int rs = 0; rs < 2; ++rs) {
        f32x4 s = (f32x4){0.f, 0.f, 0.f, 0.f};
        s = __builtin_amdgcn_mfma_f32_16x16x32_bf16(aqh[rs][0], kh0, s, 0, 0, 0);
        s = __builtin_amdgcn_mfma_f32_16x16x32_bf16(aqh[rs][0], kl0, s, 0, 0, 0);
        s = __builtin_amdgcn_mfma_f32_16x16x32_bf16(aql[rs][0], kh0, s, 0, 0, 0);
        s = __builtin_amdgcn_mfma_f32_16x16x32_bf16(aqh[rs][1], kh1, s, 0, 0, 0);
        s = __builtin_amdgcn_mfma_f32_16x16x32_bf16(aqh[rs][1], kl1, s, 0, 0, 0);
        s = __builtin_amdgcn_mfma_f32_16x16x32_bf16(aql[rs][1], kh1, s, 0, 0, 0);
        sa[rs][t4] = s;
      }
    }

    // V fragment loads (issued before softmax to hide latency — R8 placement)
    bf16x8 vv[4][2];
#pragma unroll
    for (int t4 = 0; t4 < 4; ++t4) {
      size_t vr = ((size_t)b * 64 + t4 * 16 + l16) * 2048 + kvb + lhi * 8;
      vv[t4][0] = *(const bf16x8*)(vt + vr);
      vv[t4][1] = *(const bf16x8*)(vt + vr + 32);
    }

    // causal mask; only the diagonal unit's last tile
    if (diag && tk == nt - 1) {
#pragma unroll
      for (int rs = 0; rs < 2; ++rs) {
        int qr = j * 32 + rs * 16 + lhi * 4;
#pragma unroll
        for (int t4 = 0; t4 < 4; ++t4) {
          int col = kvb + t4 * 16 + l16;
#pragma unroll
          for (int i = 0; i < 4; ++i)
            if (col > qr + i) sa[rs][t4][i] = -1e30f;
        }
      }
    }

#pragma unroll
    for (int rs = 0; rs < 2; ++rs) {
      // online softmax
      float pf[4][4];
#pragma unroll
      for (int i = 0; i < 4; ++i) {
        float tm = fmaxf(fmaxf(sa[rs][0][i], sa[rs][1][i]), fmaxf(sa[rs][2][i], sa[rs][3][i]));
#pragma unroll
        for (int d = 1; d < 16; d <<= 1) tm = fmaxf(tm, __shfl_xor(tm, d));
        float mn = fmaxf(m_r[rs][i], tm);
        float scl = __expf(m_r[rs][i] - mn);
        float rsum = 0.f;
#pragma unroll
        for (int t4 = 0; t4 < 4; ++t4) {
          float p = __expf(sa[rs][t4][i] - mn);
          pf[t4][i] = p;
          rsum += p;
        }
#pragma unroll
        for (int d = 1; d < 16; d <<= 1) rsum += __shfl_xor(rsum, d);
        l_r[rs][i] = l_r[rs][i] * scl + rsum;
        m_r[rs][i] = mn;
#pragma unroll
        for (int t4 = 0; t4 < 4; ++t4) o[rs][t4][i] *= scl;
      }

      // P -> bf16 -> per-rowset LDS (swizzled, wave-private, no barrier)
      u16* pw = (u16*)p_l[rs];
#pragma unroll
      for (int i = 0; i < 4; ++i) {
        int rr = lhi * 4 + i;
#pragma unroll
        for (int t4 = 0; t4 < 4; ++t4) {
          int col = t4 * 16 + l16;
          pw[rr * 64 + (col ^ ((rr & 7) << 3))] = f2bf(pf[t4][i]);
        }
      }
      // PV
#pragma unroll
      for (int kk = 0; kk < 2; ++kk) {
        bf16x8 ap = lds_ld8(pw, l16, kk * 32 + lhi * 8);
#pragma unroll
        for (int t4 = 0; t4 < 4; ++t4)
          o[rs][t4] = __builtin_amdgcn_mfma_f32_16x16x32_bf16(ap, vv[t4][kk], o[rs][t4], 0, 0, 0);
      }
    }
  }

  // write partials (all units); slot = blockIdx.x
  const int slot = blockIdx.x;
  float* pou = po + (size_t)slot * 2048;
#pragma unroll
  for (int rs = 0; rs < 2; ++rs)
#pragma unroll
    for (int t4 = 0; t4 < 4; ++t4) {
      int col = t4 * 16 + l16;
#pragma unroll
      for (int i = 0; i < 4; ++i)
        pou[(rs * 16 + lhi * 4 + i) * 64 + col] = o[rs][t4][i];
    }
  if (l16 == 0) {
#pragma unroll
    for (int rs = 0; rs < 2; ++rs)
#pragma unroll
      for (int i = 0; i < 4; ++i) {
        int r = rs * 16 + lhi * 4 + i;
        pml[slot * 64 + r]      = m_r[rs][i];
        pml[slot * 64 + 32 + r] = l_r[rs][i];
      }
  }
}

// ---------------------------------------------------------------------------
// Kernel 3: merge up to 8 KV-chunk partials. Grid 512 = 64 j x 8 b, 256 thr.
// ---------------------------------------------------------------------------
DEVINL int unit_of(int c, int j) {
  return (j >= 8 * c + 8) ? (c * (60 - 4 * c) + 63 - j)
                          : (224 + c * 8 + 7 - (j - 8 * c));
}

__global__ __launch_bounds__(256) void combine_kernel(const float* __restrict__ po,
                                                      const float* __restrict__ pml,
                                                      float* __restrict__ out) {
  const int b = blockIdx.x & 7, j = blockIdx.x >> 3;
  const int nu = (j >> 3) + 1;
  int slots[8];
#pragma unroll
  for (int c = 0; c < 8; ++c) slots[c] = (c < nu) ? (unit_of(c, j) * 8 + b) : 0;
  float* og = out + ((size_t)b * 2048 + j * 32) * 64;
#pragma unroll
  for (int k = 0; k < 8; ++k) {
    int e = k * 256 + threadIdx.x;
    int r = e >> 6;
    float M = -3.0e38f;
#pragma unroll
    for (int c = 0; c < 8; ++c)
      if (c < nu) M = fmaxf(M, pml[slots[c] * 64 + r]);
    float num = 0.f, den = 0.f;
#pragma unroll
    for (int c = 0; c < 8; ++c)
      if (c < nu) {
        float a = __expf(pml[slots[c] * 64 + r] - M);
        num += po[(size_t)slots[c] * 2048 + e] * a;
        den += pml[slots[c] * 64 + 32 + r] * a;
      }
    og[e] = num / den;
  }
}

// ---------------------------------------------------------------------------
extern "C" void kernel_launch(void* const* d_in, const int* in_sizes, int n_in,
                              void* d_out, int out_size, void* d_ws, size_t ws_size,
                              hipStream_t stream) {
  const float* x  = (const float*)d_in[0];
  const float* Wk = (const float*)d_in[1];
  const float* Wq = (const float*)d_in[2];
  const float* Wv = (const float*)d_in[3];
  float* out = (float*)d_out;

  const size_t QKV = (size_t)Bc * Tc * 64;       // 1,048,576 elems
  char* w = (char*)d_ws;
  u16* kb_h = (u16*)w;               w += QKV * 2;
  u16* kb_l = (u16*)w;               w += QKV * 2;
  u16* qb_h = (u16*)w;               w += QKV * 2;
  u16* qb_l = (u16*)w;               w += QKV * 2;
  u16* vt   = (u16*)w;               w += QKV * 2;
  u16* wt_s = (u16*)w;               w += (size_t)16 * 192 * 64 * 2;
  float* po = (float*)w;             w += (size_t)2304 * 2048 * 4;
  float* pml = (float*)w;            w += (size_t)2304 * 64 * 4;

  build_wt<<<768, 256, 0, stream>>>(Wk, Wq, Wv, wt_s);
  proj_kernel<<<512, 256, 0, stream>>>(x, wt_s, kb_h, kb_l, qb_h, qb_l, vt);
  attn_kernel<<<2304, 64, 0, stream>>>(qb_h, qb_l, kb_h, kb_l, vt, po, pml);
  combine_kernel<<<512, 256, 0, stream>>>(po, pml, out);
}

// Round 12
// 98.592 us; speedup vs baseline: 1.1208x; 1.1208x over previous
//
#include <hip/hip_runtime.h>
#include <hip/hip_bf16.h>

typedef unsigned short u16;
typedef __bf16 bf16x8 __attribute__((ext_vector_type(8)));
typedef _Float16 f16x8 __attribute__((ext_vector_type(8)));
typedef float f32x4 __attribute__((ext_vector_type(4)));

#define DEVINL __device__ __forceinline__

static constexpr int Bc = 8, Tc = 2048;

DEVINL u16 f2bf(float f) {
  unsigned u = __builtin_bit_cast(unsigned, f);
  unsigned r = u + 0x7fffu + ((u >> 16) & 1u);   // RNE
  return (u16)(r >> 16);
}
DEVINL float bf2f(u16 h) {
  unsigned u = ((unsigned)h) << 16;
  return __builtin_bit_cast(float, u);
}

// swizzled LDS read of 8 contiguous 16-bit elems from a [R][64] tile.
DEVINL bf16x8 lds_ld8(const u16* p, int row, int col) {
  return *(const bf16x8*)&p[row * 64 + (col ^ ((row & 7) << 3))];
}
DEVINL f16x8 lds_ld8h(const u16* p, int row, int col) {
  return *(const f16x8*)&p[row * 64 + (col ^ ((row & 7) << 3))];
}

// ---------------------------------------------------------------------------
// Kernel 0: pre-swizzled wt_s[ch][c][kc'] (f16).  Stride 12288: / and %.
// ---------------------------------------------------------------------------
__global__ __launch_bounds__(256) void build_wt(const float* __restrict__ Wk,
                                                const float* __restrict__ Wq,
                                                const float* __restrict__ Wv,
                                                u16* __restrict__ wt_s) {
  int idx = blockIdx.x * 256 + threadIdx.x;      // 16*192*64 = 196608
  int ch = idx / 12288;
  int rem = idx - ch * 12288;
  int c = rem >> 6, kc = rem & 63;
  int k = ch * 64 + (kc ^ ((c & 7) << 3));
  const float* W = (c < 64) ? Wk : (c < 128 ? Wq : Wv);
  _Float16 h = (_Float16)W[k * 64 + (c & 63)];
  wt_s[idx] = __builtin_bit_cast(u16, h);
}

// ---------------------------------------------------------------------------
// Kernel 1: fused QKV projection (unchanged from R10-measured version).
// ---------------------------------------------------------------------------
__global__ __launch_bounds__(256, 2) void proj_kernel(const float* __restrict__ x,
                                                      const u16* __restrict__ wt_s,
                                                      u16* __restrict__ kb_h, u16* __restrict__ kb_l,
                                                      u16* __restrict__ qb_h, u16* __restrict__ qb_l,
                                                      u16* __restrict__ vt) {
  __shared__ u16 wl[2][192 * 64];        // 48KB  wt chunk dbuf (pre-swizzled)
  __shared__ u16 xl[2][32 * 64];         // 8KB   x chunk dbuf (swizzled)
  const int t = threadIdx.x;
  const int w = t >> 6, lane = t & 63;
  const int l16 = lane & 15, lhi = lane >> 4;
  const int rb = blockIdx.x * 32;
  const int cb = w * 48;
  const int sr = t >> 3, sc = (t & 7) * 8;
  const f32x4* xrow = (const f32x4*)(x + (size_t)(rb + sr) * 1024 + sc);

  f32x4 acc[2][3];
#pragma unroll
  for (int a = 0; a < 2; ++a)
#pragma unroll
    for (int c = 0; c < 3; ++c) acc[a][c] = (f32x4){0.f, 0.f, 0.f, 0.f};

#define STAGE_WT(S, CH)                                                        \
  {                                                                            \
    const u16* src = wt_s + (size_t)(CH) * 12288 + t * 8;                      \
    u16* dst = &wl[S][t * 8];                                                  \
    _Pragma("unroll") for (int i = 0; i < 6; ++i)                              \
      __builtin_amdgcn_global_load_lds(                                        \
          (const __attribute__((address_space(1))) unsigned int*)(src + i * 2048), \
          (__attribute__((address_space(3))) unsigned int*)(dst + i * 2048),   \
          16, 0, 0);                                                           \
  }

#define CVT_STORE(S, F0, F1)                                                   \
  {                                                                            \
    union { _Float16 h[8]; uint4 v; } p_;                                      \
    _Pragma("unroll") for (int j = 0; j < 4; ++j) {                            \
      p_.h[j] = (_Float16)(F0)[j];                                             \
      p_.h[4 + j] = (_Float16)(F1)[j];                                         \
    }                                                                          \
    *(uint4*)&xl[S][sr * 64 + (sc ^ ((sr & 7) << 3))] = p_.v;                  \
  }

#define COMPUTE(S)                                                             \
  _Pragma("unroll") for (int kk = 0; kk < 2; ++kk) {                           \
    f16x8 a0 = lds_ld8h(xl[S], l16, kk * 32 + lhi * 8);                        \
    f16x8 a1 = lds_ld8h(xl[S], 16 + l16, kk * 32 + lhi * 8);                   \
    _Pragma("unroll") for (int tc = 0; tc < 3; ++tc) {                         \
      int c_ = cb + tc * 16 + l16;                                             \
      f16x8 bf = *(const f16x8*)&wl[S][c_ * 64 + ((kk * 32 + lhi * 8) ^ ((c_ & 7) << 3))]; \
      acc[0][tc] = __builtin_amdgcn_mfma_f32_16x16x32_f16(a0, bf, acc[0][tc], 0, 0, 0); \
      acc[1][tc] = __builtin_amdgcn_mfma_f32_16x16x32_f16(a1, bf, acc[1][tc], 0, 0, 0); \
    }                                                                          \
  }

  STAGE_WT(0, 0);
  {
    f32x4 A0 = __builtin_nontemporal_load(xrow);
    f32x4 A1 = __builtin_nontemporal_load(xrow + 1);
    CVT_STORE(0, A0, A1);
  }
  __syncthreads();

#pragma unroll 2
  for (int ch = 0; ch < 16; ++ch) {
    const int cur = ch & 1, nxt = cur ^ 1;
    f32x4 A0, A1;
    if (ch + 1 < 16) {
      STAGE_WT(nxt, ch + 1);
      A0 = __builtin_nontemporal_load(xrow + (ch + 1) * 16);
      A1 = __builtin_nontemporal_load(xrow + (ch + 1) * 16 + 1);
    }
    COMPUTE(cur);
    if (ch + 1 < 16) {
      CVT_STORE(nxt, A0, A1);
      __syncthreads();
    }
  }
#undef STAGE_WT
#undef CVT_STORE
#undef COMPUTE

#pragma unroll
  for (int ri = 0; ri < 2; ++ri) {
#pragma unroll
    for (int tc = 0; tc < 3; ++tc) {
      int gc = cb + tc * 16 + l16;
      int cc = gc & 63;
      int row = rb + ri * 16 + lhi * 4;
#pragma unroll
      for (int i = 0; i < 4; ++i) {
        float f = acc[ri][tc][i];
        int r = row + i;
        u16 h = f2bf(f);
        if (gc < 64) {
          size_t off = (size_t)r * 64 + cc;
          kb_h[off] = h; kb_l[off] = f2bf(f - bf2f(h));
        } else if (gc < 128) {
          size_t off = (size_t)r * 64 + cc;
          qb_h[off] = h; qb_l[off] = f2bf(f - bf2f(h));
        } else {
          int bb = r >> 11, tp = r & 2047;
          vt[((size_t)bb * 64 + cc) * 2048 + tp] = h;
        }
      }
    }
  }
}

// ---------------------------------------------------------------------------
// Kernel 2: causal flash attention, KV-chunk 512, 1280 blocks x 1 wave.
// NEW vs R10: register-level software pipeline. K fragments double-banked
// (A/B named regs, no runtime bank index); LOADK(next) issues before
// PROCESS(cur); V loads at top of PROCESS (use-point after softmax).
// __launch_bounds__(64) — no waves/EU min, so the ~270-VGPR live set fits
// without the compiler sinking loads to their uses (R10's VGPR=104 did that).
// ---------------------------------------------------------------------------
__global__ __launch_bounds__(64) void attn_kernel(const u16* __restrict__ qb_h,
                                                  const u16* __restrict__ qb_l,
                                                  const u16* __restrict__ kb_h,
                                                  const u16* __restrict__ kb_l,
                                                  const u16* __restrict__ vt,
                                                  float* __restrict__ po,
                                                  float* __restrict__ pml) {
  __shared__ u16 p_l[2][1024];           // per-rowset P tile (16x64, swizzled)

  const int t = threadIdx.x;             // one wave
  const int l16 = t & 15, lhi = t >> 4;
  const int u = blockIdx.x >> 3, b = blockIdx.x & 7;

  int j, c;
  if (u < 64)       { c = 0; j = 63 - u; }
  else if (u < 112) { c = 1; j = 63 - (u - 64); }
  else if (u < 144) { c = 2; j = 63 - (u - 112); }
  else              { c = 3; j = 63 - (u - 144); }

  const int kv0 = c << 9;
  const int prefix = j * 32 + 32;
  const int kv_end = (prefix < kv0 + 512) ? prefix : (kv0 + 512);
  const int nt = (kv_end - kv0 + 63) >> 6;
  const bool diag = (kv_end == prefix);

  const size_t qrow = (size_t)b * 2048 + j * 32;

  // Q fragments straight from global: lane l16 = q row, 16B contiguous cols
  bf16x8 aqh[2][2], aql[2][2];           // [rowset][kk]
#pragma unroll
  for (int rs = 0; rs < 2; ++rs)
#pragma unroll
    for (int kk = 0; kk < 2; ++kk) {
      size_t qo = (qrow + rs * 16 + l16) * 64 + kk * 32 + lhi * 8;
      aqh[rs][kk] = *(const bf16x8*)(qb_h + qo);
      aql[rs][kk] = *(const bf16x8*)(qb_l + qo);
    }

  f32x4 o[2][4];
  float m_r[2][4], l_r[2][4];
#pragma unroll
  for (int rs = 0; rs < 2; ++rs)
#pragma unroll
    for (int i = 0; i < 4; ++i) {
      o[rs][i] = (f32x4){0.f, 0.f, 0.f, 0.f};
      m_r[rs][i] = -3.0e38f; l_r[rs][i] = 0.f;
    }

  // K register banks (named; compile-time indices only)
  bf16x8 Akh0[4], Akh1[4], Akl0[4], Akl1[4];
  bf16x8 Bkh0[4], Bkh1[4], Bkl0[4], Bkl1[4];

#define LOADK(P, TK)                                                           \
  {                                                                            \
    const size_t kbase_ = ((size_t)b * 2048 + kv0 + (TK) * 64) * 64;           \
    _Pragma("unroll") for (int t4 = 0; t4 < 4; ++t4) {                         \
      size_t kr = kbase_ + (size_t)(t4 * 16 + l16) * 64 + lhi * 8;             \
      P##kh0[t4] = *(const bf16x8*)(kb_h + kr);                                \
      P##kh1[t4] = *(const bf16x8*)(kb_h + kr + 32);                           \
      P##kl0[t4] = *(const bf16x8*)(kb_l + kr);                                \
      P##kl1[t4] = *(const bf16x8*)(kb_l + kr + 32);                           \
    }                                                                          \
  }

#define PROCESS(P, TK)                                                         \
  {                                                                            \
    const int kvb_ = kv0 + (TK) * 64;                                          \
    /* V loads first: ~600cyc of QK+softmax slack before PV use */             \
    bf16x8 vv0[4], vv1[4];                                                     \
    _Pragma("unroll") for (int t4 = 0; t4 < 4; ++t4) {                         \
      size_t vr = ((size_t)b * 64 + t4 * 16 + l16) * 2048 + kvb_ + lhi * 8;    \
      vv0[t4] = *(const bf16x8*)(vt + vr);                                     \
      vv1[t4] = *(const bf16x8*)(vt + vr + 32);                                \
    }                                                                          \
    f32x4 sa[2][4];                                                            \
    _Pragma("unroll") for (int t4 = 0; t4 < 4; ++t4) {                         \
      _Pragma("unroll") for (int rs = 0; rs < 2; ++rs) {                       \
        f32x4 s = (f32x4){0.f, 0.f, 0.f, 0.f};                                 \
        s = __builtin_amdgcn_mfma_f32_16x16x32_bf16(aqh[rs][0], P##kh0[t4], s, 0, 0, 0); \
        s = __builtin_amdgcn_mfma_f32_16x16x32_bf16(aqh[rs][0], P##kl0[t4], s, 0, 0, 0); \
        s = __builtin_amdgcn_mfma_f32_16x16x32_bf16(aql[rs][0], P##kh0[t4], s, 0, 0, 0); \
        s = __builtin_amdgcn_mfma_f32_16x16x32_bf16(aqh[rs][1], P##kh1[t4], s, 0, 0, 0); \
        s = __builtin_amdgcn_mfma_f32_16x16x32_bf16(aqh[rs][1], P##kl1[t4], s, 0, 0, 0); \
        s = __builtin_amdgcn_mfma_f32_16x16x32_bf16(aql[rs][1], P##kh1[t4], s, 0, 0, 0); \
        sa[rs][t4] = s;                                                        \
      }                                                                        \
    }                                                                          \
    if (diag && (TK) == nt - 1) {                                              \
      _Pragma("unroll") for (int rs = 0; rs < 2; ++rs) {                       \
        int qr = j * 32 + rs * 16 + lhi * 4;                                   \
        _Pragma("unroll") for (int t4 = 0; t4 < 4; ++t4) {                     \
          int col = kvb_ + t4 * 16 + l16;                                      \
          _Pragma("unroll") for (int i = 0; i < 4; ++i)                        \
            if (col > qr + i) sa[rs][t4][i] = -1e30f;                          \
        }                                                                      \
      }                                                                        \
    }                                                                          \
    _Pragma("unroll") for (int rs = 0; rs < 2; ++rs) {                         \
      float pf[4][4];                                                          \
      _Pragma("unroll") for (int i = 0; i < 4; ++i) {                          \
        float tm = fmaxf(fmaxf(sa[rs][0][i], sa[rs][1][i]), fmaxf(sa[rs][2][i], sa[rs][3][i])); \
        _Pragma("unroll") for (int d = 1; d < 16; d <<= 1) tm = fmaxf(tm, __shfl_xor(tm, d)); \
        float mn = fmaxf(m_r[rs][i], tm);                                      \
        float scl = __expf(m_r[rs][i] - mn);                                   \
        float rsum = 0.f;                                                      \
        _Pragma("unroll") for (int t4 = 0; t4 < 4; ++t4) {                     \
          float p = __expf(sa[rs][t4][i] - mn);                                \
          pf[t4][i] = p;                                                       \
          rsum += p;                                                           \
        }                                                                      \
        _Pragma("unroll") for (int d = 1; d < 16; d <<= 1) rsum += __shfl_xor(rsum, d); \
        l_r[rs][i] = l_r[rs][i] * scl + rsum;                                  \
        m_r[rs][i] = mn;                                                       \
        _Pragma("unroll") for (int t4 = 0; t4 < 4; ++t4) o[rs][t4][i] *= scl;  \
      }                                                                        \
      u16* pw = (u16*)p_l[rs];                                                 \
      _Pragma("unroll") for (int i = 0; i < 4; ++i) {                          \
        int rr = lhi * 4 + i;                                                  \
        _Pragma("unroll") for (int t4 = 0; t4 < 4; ++t4) {                     \
          int col = t4 * 16 + l16;                                             \
          pw[rr * 64 + (col ^ ((rr & 7) << 3))] = f2bf(pf[t4][i]);             \
        }                                                                      \
      }                                                                        \
      {                                                                        \
        bf16x8 ap0 = lds_ld8(pw, l16, lhi * 8);                                \
        bf16x8 ap1 = lds_ld8(pw, l16, 32 + lhi * 8);                           \
        _Pragma("unroll") for (int t4 = 0; t4 < 4; ++t4) {                     \
          o[rs][t4] = __builtin_amdgcn_mfma_f32_16x16x32_bf16(ap0, vv0[t4], o[rs][t4], 0, 0, 0); \
          o[rs][t4] = __builtin_amdgcn_mfma_f32_16x16x32_bf16(ap1, vv1[t4], o[rs][t4], 0, 0, 0); \
        }                                                                      \
      }                                                                        \
    }                                                                          \
  }

  // 2-deep pipeline: LOADK(next) issues before PROCESS(cur)
  LOADK(A, 0);
  for (int tp = 0; tp < nt; tp += 2) {
    if (tp + 1 < nt) LOADK(B, tp + 1);
    PROCESS(A, tp);
    if (tp + 2 < nt) LOADK(A, tp + 2);
    if (tp + 1 < nt) PROCESS(B, tp + 1);
  }
#undef LOADK
#undef PROCESS

  // write partials (all units)
  const int slot = blockIdx.x;
  float* pou = po + (size_t)slot * 2048;
#pragma unroll
  for (int rs = 0; rs < 2; ++rs)
#pragma unroll
    for (int t4 = 0; t4 < 4; ++t4) {
      int col = t4 * 16 + l16;
#pragma unroll
      for (int i = 0; i < 4; ++i)
        pou[(rs * 16 + lhi * 4 + i) * 64 + col] = o[rs][t4][i];
    }
  if (l16 == 0) {
#pragma unroll
    for (int rs = 0; rs < 2; ++rs)
#pragma unroll
      for (int i = 0; i < 4; ++i) {
        int r = rs * 16 + lhi * 4 + i;
        pml[slot * 64 + r]      = m_r[rs][i];
        pml[slot * 64 + 32 + r] = l_r[rs][i];
      }
  }
}

// ---------------------------------------------------------------------------
// Kernel 3: merge up to 4 KV-chunk partials. Grid 512 = 64 j x 8 b, 256 thr.
// ---------------------------------------------------------------------------
__global__ __launch_bounds__(256) void combine_kernel(const float* __restrict__ po,
                                                      const float* __restrict__ pml,
                                                      float* __restrict__ out) {
  const int b = blockIdx.x & 7, j = blockIdx.x >> 3;
  const int nu = (j >> 4) + 1;
  const int s0 = ((0)   + 63 - j) * 8 + b;
  const int s1 = ((64)  + 63 - j) * 8 + b;
  const int s2 = ((112) + 63 - j) * 8 + b;
  const int s3 = ((144) + 63 - j) * 8 + b;
  float* og = out + ((size_t)b * 2048 + j * 32) * 64;
#pragma unroll
  for (int k = 0; k < 8; ++k) {
    int e = k * 256 + threadIdx.x;
    int r = e >> 6;
    float M = pml[s0 * 64 + r];
    if (nu > 1) M = fmaxf(M, pml[s1 * 64 + r]);
    if (nu > 2) M = fmaxf(M, pml[s2 * 64 + r]);
    if (nu > 3) M = fmaxf(M, pml[s3 * 64 + r]);
    float num, den;
    {
      float a = __expf(pml[s0 * 64 + r] - M);
      num = po[(size_t)s0 * 2048 + e] * a;
      den = pml[s0 * 64 + 32 + r] * a;
    }
    if (nu > 1) {
      float a = __expf(pml[s1 * 64 + r] - M);
      num += po[(size_t)s1 * 2048 + e] * a;
      den += pml[s1 * 64 + 32 + r] * a;
    }
    if (nu > 2) {
      float a = __expf(pml[s2 * 64 + r] - M);
      num += po[(size_t)s2 * 2048 + e] * a;
      den += pml[s2 * 64 + 32 + r] * a;
    }
    if (nu > 3) {
      float a = __expf(pml[s3 * 64 + r] - M);
      num += po[(size_t)s3 * 2048 + e] * a;
      den += pml[s3 * 64 + 32 + r] * a;
    }
    og[e] = num / den;
  }
}

// ---------------------------------------------------------------------------
extern "C" void kernel_launch(void* const* d_in, const int* in_sizes, int n_in,
                              void* d_out, int out_size, void* d_ws, size_t ws_size,
                              hipStream_t stream) {
  const float* x  = (const float*)d_in[0];
  const float* Wk = (const float*)d_in[1];
  const float* Wq = (const float*)d_in[2];
  const float* Wv = (const float*)d_in[3];
  float* out = (float*)d_out;

  const size_t QKV = (size_t)Bc * Tc * 64;       // 1,048,576 elems
  char* w = (char*)d_ws;
  u16* kb_h = (u16*)w;               w += QKV * 2;
  u16* kb_l = (u16*)w;               w += QKV * 2;
  u16* qb_h = (u16*)w;               w += QKV * 2;
  u16* qb_l = (u16*)w;               w += QKV * 2;
  u16* vt   = (u16*)w;               w += QKV * 2;
  u16* wt_s = (u16*)w;               w += (size_t)16 * 192 * 64 * 2;
  float* po = (float*)w;             w += (size_t)1280 * 2048 * 4;
  float* pml = (float*)w;            w += (size_t)1280 * 64 * 4;

  build_wt<<<768, 256, 0, stream>>>(Wk, Wq, Wv, wt_s);
  proj_kernel<<<512, 256, 0, stream>>>(x, wt_s, kb_h, kb_l, qb_h, qb_l, vt);
  attn_kernel<<<1280, 64, 0, stream>>>(qb_h, qb_l, kb_h, kb_l, vt, po, pml);
  combine_kernel<<<512, 256, 0, stream>>>(po, pml, out);
}

// Round 13
// 81.086 us; speedup vs baseline: 1.3628x; 1.2159x over previous
//
#include <hip/hip_runtime.h>
#include <hip/hip_bf16.h>

typedef unsigned short u16;
typedef __bf16 bf16x8 __attribute__((ext_vector_type(8)));
typedef _Float16 f16x8 __attribute__((ext_vector_type(8)));
typedef float f32x4 __attribute__((ext_vector_type(4)));

#define DEVINL __device__ __forceinline__

static constexpr int Bc = 8, Tc = 2048;

DEVINL u16 f2bf(float f) {
  unsigned u = __builtin_bit_cast(unsigned, f);
  unsigned r = u + 0x7fffu + ((u >> 16) & 1u);   // RNE
  return (u16)(r >> 16);
}
DEVINL float bf2f(u16 h) {
  unsigned u = ((unsigned)h) << 16;
  return __builtin_bit_cast(float, u);
}

// swizzled LDS read of 8 contiguous 16-bit elems from a [R][64] tile.
DEVINL bf16x8 lds_ld8(const u16* p, int row, int col) {
  return *(const bf16x8*)&p[row * 64 + (col ^ ((row & 7) << 3))];
}
DEVINL f16x8 lds_ld8h(const u16* p, int row, int col) {
  return *(const f16x8*)&p[row * 64 + (col ^ ((row & 7) << 3))];
}

// ---------------------------------------------------------------------------
// Kernel 0: pre-swizzled wt_s[ch][c][kc'] (f16).  Stride 12288: / and %.
// ---------------------------------------------------------------------------
__global__ __launch_bounds__(256) void build_wt(const float* __restrict__ Wk,
                                                const float* __restrict__ Wq,
                                                const float* __restrict__ Wv,
                                                u16* __restrict__ wt_s) {
  int idx = blockIdx.x * 256 + threadIdx.x;      // 16*192*64 = 196608
  int ch = idx / 12288;
  int rem = idx - ch * 12288;
  int c = rem >> 6, kc = rem & 63;
  int k = ch * 64 + (kc ^ ((c & 7) << 3));
  const float* W = (c < 64) ? Wk : (c < 128 ? Wq : Wv);
  _Float16 h = (_Float16)W[k * 64 + (c & 63)];
  wt_s[idx] = __builtin_bit_cast(u16, h);
}

// ---------------------------------------------------------------------------
// Kernel 1: fused QKV projection (unchanged from R10-measured version).
// ---------------------------------------------------------------------------
__global__ __launch_bounds__(256, 2) void proj_kernel(const float* __restrict__ x,
                                                      const u16* __restrict__ wt_s,
                                                      u16* __restrict__ kb_h, u16* __restrict__ kb_l,
                                                      u16* __restrict__ qb_h, u16* __restrict__ qb_l,
                                                      u16* __restrict__ vt) {
  __shared__ u16 wl[2][192 * 64];        // 48KB  wt chunk dbuf (pre-swizzled)
  __shared__ u16 xl[2][32 * 64];         // 8KB   x chunk dbuf (swizzled)
  const int t = threadIdx.x;
  const int w = t >> 6, lane = t & 63;
  const int l16 = lane & 15, lhi = lane >> 4;
  const int rb = blockIdx.x * 32;
  const int cb = w * 48;
  const int sr = t >> 3, sc = (t & 7) * 8;
  const f32x4* xrow = (const f32x4*)(x + (size_t)(rb + sr) * 1024 + sc);

  f32x4 acc[2][3];
#pragma unroll
  for (int a = 0; a < 2; ++a)
#pragma unroll
    for (int c = 0; c < 3; ++c) acc[a][c] = (f32x4){0.f, 0.f, 0.f, 0.f};

#define STAGE_WT(S, CH)                                                        \
  {                                                                            \
    const u16* src = wt_s + (size_t)(CH) * 12288 + t * 8;                      \
    u16* dst = &wl[S][t * 8];                                                  \
    _Pragma("unroll") for (int i = 0; i < 6; ++i)                              \
      __builtin_amdgcn_global_load_lds(                                        \
          (const __attribute__((address_space(1))) unsigned int*)(src + i * 2048), \
          (__attribute__((address_space(3))) unsigned int*)(dst + i * 2048),   \
          16, 0, 0);                                                           \
  }

#define CVT_STORE(S, F0, F1)                                                   \
  {                                                                            \
    union { _Float16 h[8]; uint4 v; } p_;                                      \
    _Pragma("unroll") for (int j = 0; j < 4; ++j) {                            \
      p_.h[j] = (_Float16)(F0)[j];                                             \
      p_.h[4 + j] = (_Float16)(F1)[j];                                         \
    }                                                                          \
    *(uint4*)&xl[S][sr * 64 + (sc ^ ((sr & 7) << 3))] = p_.v;                  \
  }

#define COMPUTE(S)                                                             \
  _Pragma("unroll") for (int kk = 0; kk < 2; ++kk) {                           \
    f16x8 a0 = lds_ld8h(xl[S], l16, kk * 32 + lhi * 8);                        \
    f16x8 a1 = lds_ld8h(xl[S], 16 + l16, kk * 32 + lhi * 8);                   \
    _Pragma("unroll") for (int tc = 0; tc < 3; ++tc) {                         \
      int c_ = cb + tc * 16 + l16;                                             \
      f16x8 bf = *(const f16x8*)&wl[S][c_ * 64 + ((kk * 32 + lhi * 8) ^ ((c_ & 7) << 3))]; \
      acc[0][tc] = __builtin_amdgcn_mfma_f32_16x16x32_f16(a0, bf, acc[0][tc], 0, 0, 0); \
      acc[1][tc] = __builtin_amdgcn_mfma_f32_16x16x32_f16(a1, bf, acc[1][tc], 0, 0, 0); \
    }                                                                          \
  }

  STAGE_WT(0, 0);
  {
    f32x4 A0 = __builtin_nontemporal_load(xrow);
    f32x4 A1 = __builtin_nontemporal_load(xrow + 1);
    CVT_STORE(0, A0, A1);
  }
  __syncthreads();

#pragma unroll 2
  for (int ch = 0; ch < 16; ++ch) {
    const int cur = ch & 1, nxt = cur ^ 1;
    f32x4 A0, A1;
    if (ch + 1 < 16) {
      STAGE_WT(nxt, ch + 1);
      A0 = __builtin_nontemporal_load(xrow + (ch + 1) * 16);
      A1 = __builtin_nontemporal_load(xrow + (ch + 1) * 16 + 1);
    }
    COMPUTE(cur);
    if (ch + 1 < 16) {
      CVT_STORE(nxt, A0, A1);
      __syncthreads();
    }
  }
#undef STAGE_WT
#undef CVT_STORE
#undef COMPUTE

#pragma unroll
  for (int ri = 0; ri < 2; ++ri) {
#pragma unroll
    for (int tc = 0; tc < 3; ++tc) {
      int gc = cb + tc * 16 + l16;
      int cc = gc & 63;
      int row = rb + ri * 16 + lhi * 4;
#pragma unroll
      for (int i = 0; i < 4; ++i) {
        float f = acc[ri][tc][i];
        int r = row + i;
        u16 h = f2bf(f);
        if (gc < 64) {
          size_t off = (size_t)r * 64 + cc;
          kb_h[off] = h; kb_l[off] = f2bf(f - bf2f(h));
        } else if (gc < 128) {
          size_t off = (size_t)r * 64 + cc;
          qb_h[off] = h; qb_l[off] = f2bf(f - bf2f(h));
        } else {
          int bb = r >> 11, tp = r & 2047;
          vt[((size_t)bb * 64 + cc) * 2048 + tp] = h;
        }
      }
    }
  }
}

// ---------------------------------------------------------------------------
// Kernel 2: causal flash attention, IN-BLOCK flash-decoding.
// 512 blocks (8 b x 64 j, longest-first) x 4 waves (256 thr).
// Wave w processes KV tiles tk = w, w+4, ... with private (o,m,l) — the
// R10-measured per-tile body verbatim. Final in-LDS merge of 4 partials
// writes `out` directly: combine kernel + po/pml partial traffic GONE.
// ---------------------------------------------------------------------------
__global__ __launch_bounds__(256, 2) void attn_kernel(const u16* __restrict__ qb_h,
                                                      const u16* __restrict__ qb_l,
                                                      const u16* __restrict__ kb_h,
                                                      const u16* __restrict__ kb_l,
                                                      const u16* __restrict__ vt,
                                                      float* __restrict__ out) {
  __shared__ u16 p_l[4][2][1024];        // per-wave per-rowset P tile (16KB)
  __shared__ float om[4][32][64];        // per-wave O partials (32KB)
  __shared__ float ml[4][2][32];         // per-wave m/l partials (1KB)

  const int t = threadIdx.x, w = t >> 6, lane = t & 63;
  const int l16 = lane & 15, lhi = lane >> 4;
  const int b = blockIdx.x & 7, j = 63 - (blockIdx.x >> 3);
  const int ntt = (j + 2) >> 1;          // ceil((j*32+32)/64)
  const size_t qrow = (size_t)b * 2048 + j * 32;

  // Q fragments straight from global: lane l16 = q row, 16B contiguous cols
  bf16x8 aqh[2][2], aql[2][2];           // [rowset][kk]
#pragma unroll
  for (int rs = 0; rs < 2; ++rs)
#pragma unroll
    for (int kk = 0; kk < 2; ++kk) {
      size_t qo = (qrow + rs * 16 + l16) * 64 + kk * 32 + lhi * 8;
      aqh[rs][kk] = *(const bf16x8*)(qb_h + qo);
      aql[rs][kk] = *(const bf16x8*)(qb_l + qo);
    }

  f32x4 o[2][4];
  float m_r[2][4], l_r[2][4];
#pragma unroll
  for (int rs = 0; rs < 2; ++rs)
#pragma unroll
    for (int i = 0; i < 4; ++i) {
      o[rs][i] = (f32x4){0.f, 0.f, 0.f, 0.f};
      m_r[rs][i] = -3.0e38f; l_r[rs][i] = 0.f;
    }

  for (int tk = w; tk < ntt; tk += 4) {
    const int kvb = tk * 64;
    const size_t kbase = ((size_t)b * 2048 + kvb) * 64;

    // S = Q K^T: K frags loaded per-t4 (transient regs) — R10 body
    f32x4 sa[2][4];
#pragma unroll
    for (int t4 = 0; t4 < 4; ++t4) {
      size_t kr = kbase + (size_t)(t4 * 16 + l16) * 64 + lhi * 8;
      bf16x8 kh0 = *(const bf16x8*)(kb_h + kr);
      bf16x8 kh1 = *(const bf16x8*)(kb_h + kr + 32);
      bf16x8 kl0 = *(const bf16x8*)(kb_l + kr);
      bf16x8 kl1 = *(const bf16x8*)(kb_l + kr + 32);
#pragma unroll
      for (int rs = 0; rs < 2; ++rs) {
        f32x4 s = (f32x4){0.f, 0.f, 0.f, 0.f};
        s = __builtin_amdgcn_mfma_f32_16x16x32_bf16(aqh[rs][0], kh0, s, 0, 0, 0);
        s = __builtin_amdgcn_mfma_f32_16x16x32_bf16(aqh[rs][0], kl0, s, 0, 0, 0);
        s = __builtin_amdgcn_mfma_f32_16x16x32_bf16(aql[rs][0], kh0, s, 0, 0, 0);
        s = __builtin_amdgcn_mfma_f32_16x16x32_bf16(aqh[rs][1], kh1, s, 0, 0, 0);
        s = __builtin_amdgcn_mfma_f32_16x16x32_bf16(aqh[rs][1], kl1, s, 0, 0, 0);
        s = __builtin_amdgcn_mfma_f32_16x16x32_bf16(aql[rs][1], kh1, s, 0, 0, 0);
        sa[rs][t4] = s;
      }
    }

    // V fragment loads (issued before softmax to hide latency)
    bf16x8 vv[4][2];
#pragma unroll
    for (int t4 = 0; t4 < 4; ++t4) {
      size_t vr = ((size_t)b * 64 + t4 * 16 + l16) * 2048 + kvb + lhi * 8;
      vv[t4][0] = *(const bf16x8*)(vt + vr);
      vv[t4][1] = *(const bf16x8*)(vt + vr + 32);
    }

    // causal mask: only the tile that can cross the diagonal (tk == ntt-1)
    if (tk == ntt - 1) {
#pragma unroll
      for (int rs = 0; rs < 2; ++rs) {
        int qr = j * 32 + rs * 16 + lhi * 4;
#pragma unroll
        for (int t4 = 0; t4 < 4; ++t4) {
          int col = kvb + t4 * 16 + l16;
#pragma unroll
          for (int i = 0; i < 4; ++i)
            if (col > qr + i) sa[rs][t4][i] = -1e30f;
        }
      }
    }

#pragma unroll
    for (int rs = 0; rs < 2; ++rs) {
      // online softmax
      float pf[4][4];
#pragma unroll
      for (int i = 0; i < 4; ++i) {
        float tm = fmaxf(fmaxf(sa[rs][0][i], sa[rs][1][i]), fmaxf(sa[rs][2][i], sa[rs][3][i]));
#pragma unroll
        for (int d = 1; d < 16; d <<= 1) tm = fmaxf(tm, __shfl_xor(tm, d));
        float mn = fmaxf(m_r[rs][i], tm);
        float scl = __expf(m_r[rs][i] - mn);
        float rsum = 0.f;
#pragma unroll
        for (int t4 = 0; t4 < 4; ++t4) {
          float p = __expf(sa[rs][t4][i] - mn);
          pf[t4][i] = p;
          rsum += p;
        }
#pragma unroll
        for (int d = 1; d < 16; d <<= 1) rsum += __shfl_xor(rsum, d);
        l_r[rs][i] = l_r[rs][i] * scl + rsum;
        m_r[rs][i] = mn;
#pragma unroll
        for (int t4 = 0; t4 < 4; ++t4) o[rs][t4][i] *= scl;
      }

      // P -> bf16 -> wave-private LDS (swizzled, no barrier)
      u16* pw = (u16*)p_l[w][rs];
#pragma unroll
      for (int i = 0; i < 4; ++i) {
        int rr = lhi * 4 + i;
#pragma unroll
        for (int t4 = 0; t4 < 4; ++t4) {
          int col = t4 * 16 + l16;
          pw[rr * 64 + (col ^ ((rr & 7) << 3))] = f2bf(pf[t4][i]);
        }
      }
      // PV
#pragma unroll
      for (int kk = 0; kk < 2; ++kk) {
        bf16x8 ap = lds_ld8(pw, l16, kk * 32 + lhi * 8);
#pragma unroll
        for (int t4 = 0; t4 < 4; ++t4)
          o[rs][t4] = __builtin_amdgcn_mfma_f32_16x16x32_bf16(ap, vv[t4][kk], o[rs][t4], 0, 0, 0);
      }
    }
  }

  // publish per-wave partials to LDS
#pragma unroll
  for (int rs = 0; rs < 2; ++rs)
#pragma unroll
    for (int t4 = 0; t4 < 4; ++t4) {
      int col = t4 * 16 + l16;
#pragma unroll
      for (int i = 0; i < 4; ++i)
        om[w][rs * 16 + lhi * 4 + i][col] = o[rs][t4][i];
    }
  if (l16 == 0) {
#pragma unroll
    for (int rs = 0; rs < 2; ++rs)
#pragma unroll
      for (int i = 0; i < 4; ++i) {
        int r = rs * 16 + lhi * 4 + i;
        ml[w][0][r] = m_r[rs][i];
        ml[w][1][r] = l_r[rs][i];
      }
  }
  __syncthreads();

  // in-block merge: thread t -> row t>>3, cols (t&7)*8..+7; write out direct.
  // Empty waves have m=-inf, l=0 -> exp(-inf - M) = 0 (M finite: wave 0
  // always has tile 0), contributing nothing.
  {
    int r = t >> 3, c0 = (t & 7) * 8;
    float m0 = ml[0][0][r], m1 = ml[1][0][r], m2 = ml[2][0][r], m3 = ml[3][0][r];
    float M = fmaxf(fmaxf(m0, m1), fmaxf(m2, m3));
    float a0 = __expf(m0 - M), a1 = __expf(m1 - M);
    float a2 = __expf(m2 - M), a3 = __expf(m3 - M);
    float den = ml[0][1][r] * a0 + ml[1][1][r] * a1 + ml[2][1][r] * a2 + ml[3][1][r] * a3;
    float inv = 1.f / den;
    float* og = out + (qrow + r) * 64 + c0;
#pragma unroll
    for (int cc = 0; cc < 8; ++cc) {
      float v = om[0][r][c0 + cc] * a0 + om[1][r][c0 + cc] * a1 +
                om[2][r][c0 + cc] * a2 + om[3][r][c0 + cc] * a3;
      og[cc] = v * inv;
    }
  }
}

// ---------------------------------------------------------------------------
extern "C" void kernel_launch(void* const* d_in, const int* in_sizes, int n_in,
                              void* d_out, int out_size, void* d_ws, size_t ws_size,
                              hipStream_t stream) {
  const float* x  = (const float*)d_in[0];
  const float* Wk = (const float*)d_in[1];
  const float* Wq = (const float*)d_in[2];
  const float* Wv = (const float*)d_in[3];
  float* out = (float*)d_out;

  const size_t QKV = (size_t)Bc * Tc * 64;       // 1,048,576 elems
  char* w = (char*)d_ws;
  u16* kb_h = (u16*)w;               w += QKV * 2;
  u16* kb_l = (u16*)w;               w += QKV * 2;
  u16* qb_h = (u16*)w;               w += QKV * 2;
  u16* qb_l = (u16*)w;               w += QKV * 2;
  u16* vt   = (u16*)w;               w += QKV * 2;
  u16* wt_s = (u16*)w;               w += (size_t)16 * 192 * 64 * 2;

  build_wt<<<768, 256, 0, stream>>>(Wk, Wq, Wv, wt_s);
  proj_kernel<<<512, 256, 0, stream>>>(x, wt_s, kb_h, kb_l, qb_h, qb_l, vt);
  attn_kernel<<<512, 256, 0, stream>>>(qb_h, qb_l, kb_h, kb_l, vt, out);
}

// Round 14
// 67.345 us; speedup vs baseline: 1.6408x; 1.2040x over previous
//
#include <hip/hip_runtime.h>
#include <hip/hip_bf16.h>

typedef unsigned short u16;
typedef __bf16 bf16x8 __attribute__((ext_vector_type(8)));
typedef _Float16 f16x8 __attribute__((ext_vector_type(8)));
typedef float f32x4 __attribute__((ext_vector_type(4)));

#define DEVINL __device__ __forceinline__

static constexpr int Bc = 8, Tc = 2048;

DEVINL u16 f2bf(float f) {
  unsigned u = __builtin_bit_cast(unsigned, f);
  unsigned r = u + 0x7fffu + ((u >> 16) & 1u);   // RNE
  return (u16)(r >> 16);
}
DEVINL float bf2f(u16 h) {
  unsigned u = ((unsigned)h) << 16;
  return __builtin_bit_cast(float, u);
}

// swizzled LDS read of 8 contiguous 16-bit elems from a [R][64] tile.
DEVINL bf16x8 lds_ld8(const u16* p, int row, int col) {
  return *(const bf16x8*)&p[row * 64 + (col ^ ((row & 7) << 3))];
}
DEVINL f16x8 lds_ld8h(const u16* p, int row, int col) {
  return *(const f16x8*)&p[row * 64 + (col ^ ((row & 7) << 3))];
}

// ---------------------------------------------------------------------------
// Kernel 0: pre-swizzled wt_s[ch][c][kc'] (f16).  Stride 12288: / and %.
// ---------------------------------------------------------------------------
__global__ __launch_bounds__(256) void build_wt(const float* __restrict__ Wk,
                                                const float* __restrict__ Wq,
                                                const float* __restrict__ Wv,
                                                u16* __restrict__ wt_s) {
  int idx = blockIdx.x * 256 + threadIdx.x;      // 16*192*64 = 196608
  int ch = idx / 12288;
  int rem = idx - ch * 12288;
  int c = rem >> 6, kc = rem & 63;
  int k = ch * 64 + (kc ^ ((c & 7) << 3));
  const float* W = (c < 64) ? Wk : (c < 128 ? Wq : Wv);
  _Float16 h = (_Float16)W[k * 64 + (c & 63)];
  wt_s[idx] = __builtin_bit_cast(u16, h);
}

// ---------------------------------------------------------------------------
// Kernel 1: fused QKV projection. R10 body; NEW epilogue: q,k stored as
// f16 SINGLE (no hi/lo) — QK^T error budget covered by f16's 11-bit mantissa.
// V TRANSPOSED [b][d][t] bf16 (PV unchanged).
// ---------------------------------------------------------------------------
__global__ __launch_bounds__(256, 2) void proj_kernel(const float* __restrict__ x,
                                                      const u16* __restrict__ wt_s,
                                                      u16* __restrict__ kb,
                                                      u16* __restrict__ qb,
                                                      u16* __restrict__ vt) {
  __shared__ u16 wl[2][192 * 64];        // 48KB  wt chunk dbuf (pre-swizzled)
  __shared__ u16 xl[2][32 * 64];         // 8KB   x chunk dbuf (swizzled)
  const int t = threadIdx.x;
  const int w = t >> 6, lane = t & 63;
  const int l16 = lane & 15, lhi = lane >> 4;
  const int rb = blockIdx.x * 32;
  const int cb = w * 48;
  const int sr = t >> 3, sc = (t & 7) * 8;
  const f32x4* xrow = (const f32x4*)(x + (size_t)(rb + sr) * 1024 + sc);

  f32x4 acc[2][3];
#pragma unroll
  for (int a = 0; a < 2; ++a)
#pragma unroll
    for (int c = 0; c < 3; ++c) acc[a][c] = (f32x4){0.f, 0.f, 0.f, 0.f};

#define STAGE_WT(S, CH)                                                        \
  {                                                                            \
    const u16* src = wt_s + (size_t)(CH) * 12288 + t * 8;                      \
    u16* dst = &wl[S][t * 8];                                                  \
    _Pragma("unroll") for (int i = 0; i < 6; ++i)                              \
      __builtin_amdgcn_global_load_lds(                                        \
          (const __attribute__((address_space(1))) unsigned int*)(src + i * 2048), \
          (__attribute__((address_space(3))) unsigned int*)(dst + i * 2048),   \
          16, 0, 0);                                                           \
  }

#define CVT_STORE(S, F0, F1)                                                   \
  {                                                                            \
    union { _Float16 h[8]; uint4 v; } p_;                                      \
    _Pragma("unroll") for (int j = 0; j < 4; ++j) {                            \
      p_.h[j] = (_Float16)(F0)[j];                                             \
      p_.h[4 + j] = (_Float16)(F1)[j];                                         \
    }                                                                          \
    *(uint4*)&xl[S][sr * 64 + (sc ^ ((sr & 7) << 3))] = p_.v;                  \
  }

#define COMPUTE(S)                                                             \
  _Pragma("unroll") for (int kk = 0; kk < 2; ++kk) {                           \
    f16x8 a0 = lds_ld8h(xl[S], l16, kk * 32 + lhi * 8);                        \
    f16x8 a1 = lds_ld8h(xl[S], 16 + l16, kk * 32 + lhi * 8);                   \
    _Pragma("unroll") for (int tc = 0; tc < 3; ++tc) {                         \
      int c_ = cb + tc * 16 + l16;                                             \
      f16x8 bf = *(const f16x8*)&wl[S][c_ * 64 + ((kk * 32 + lhi * 8) ^ ((c_ & 7) << 3))]; \
      acc[0][tc] = __builtin_amdgcn_mfma_f32_16x16x32_f16(a0, bf, acc[0][tc], 0, 0, 0); \
      acc[1][tc] = __builtin_amdgcn_mfma_f32_16x16x32_f16(a1, bf, acc[1][tc], 0, 0, 0); \
    }                                                                          \
  }

  STAGE_WT(0, 0);
  {
    f32x4 A0 = __builtin_nontemporal_load(xrow);
    f32x4 A1 = __builtin_nontemporal_load(xrow + 1);
    CVT_STORE(0, A0, A1);
  }
  __syncthreads();

#pragma unroll 2
  for (int ch = 0; ch < 16; ++ch) {
    const int cur = ch & 1, nxt = cur ^ 1;
    f32x4 A0, A1;
    if (ch + 1 < 16) {
      STAGE_WT(nxt, ch + 1);
      A0 = __builtin_nontemporal_load(xrow + (ch + 1) * 16);
      A1 = __builtin_nontemporal_load(xrow + (ch + 1) * 16 + 1);
    }
    COMPUTE(cur);
    if (ch + 1 < 16) {
      CVT_STORE(nxt, A0, A1);
      __syncthreads();
    }
  }
#undef STAGE_WT
#undef CVT_STORE
#undef COMPUTE

  // epilogue: k,q -> f16 single; v -> bf16 transposed
#pragma unroll
  for (int ri = 0; ri < 2; ++ri) {
#pragma unroll
    for (int tc = 0; tc < 3; ++tc) {
      int gc = cb + tc * 16 + l16;
      int cc = gc & 63;
      int row = rb + ri * 16 + lhi * 4;
#pragma unroll
      for (int i = 0; i < 4; ++i) {
        float f = acc[ri][tc][i];
        int r = row + i;
        if (gc < 64) {
          _Float16 h = (_Float16)f;
          kb[(size_t)r * 64 + cc] = __builtin_bit_cast(u16, h);
        } else if (gc < 128) {
          _Float16 h = (_Float16)f;
          qb[(size_t)r * 64 + cc] = __builtin_bit_cast(u16, h);
        } else {
          int bb = r >> 11, tp = r & 2047;
          vt[((size_t)bb * 64 + cc) * 2048 + tp] = f2bf(f);
        }
      }
    }
  }
}

// ---------------------------------------------------------------------------
// Kernel 2: causal flash attention, IN-BLOCK flash-decoding (R13 structure).
// 512 blocks (8 b x 64 j, longest-first) x 4 waves (256 thr).
// NEW vs R13: Q,K are f16 single -> QK^T is 2 chained MFMAs per (rs,t4)
// (was 6 hi/lo), K-load bytes halved. PV (bf16 P,V) unchanged.
// ---------------------------------------------------------------------------
__global__ __launch_bounds__(256, 2) void attn_kernel(const u16* __restrict__ qb,
                                                      const u16* __restrict__ kb,
                                                      const u16* __restrict__ vt,
                                                      float* __restrict__ out) {
  __shared__ u16 p_l[4][2][1024];        // per-wave per-rowset P tile (16KB)
  __shared__ float om[4][32][64];        // per-wave O partials (32KB)
  __shared__ float ml[4][2][32];         // per-wave m/l partials (1KB)

  const int t = threadIdx.x, w = t >> 6, lane = t & 63;
  const int l16 = lane & 15, lhi = lane >> 4;
  const int b = blockIdx.x & 7, j = 63 - (blockIdx.x >> 3);
  const int ntt = (j + 2) >> 1;          // ceil((j*32+32)/64)
  const size_t qrow = (size_t)b * 2048 + j * 32;

  // Q fragments straight from global (f16): lane l16 = q row, 16B contiguous
  f16x8 aq[2][2];                        // [rowset][kk]
#pragma unroll
  for (int rs = 0; rs < 2; ++rs)
#pragma unroll
    for (int kk = 0; kk < 2; ++kk) {
      size_t qo = (qrow + rs * 16 + l16) * 64 + kk * 32 + lhi * 8;
      aq[rs][kk] = *(const f16x8*)(qb + qo);
    }

  f32x4 o[2][4];
  float m_r[2][4], l_r[2][4];
#pragma unroll
  for (int rs = 0; rs < 2; ++rs)
#pragma unroll
    for (int i = 0; i < 4; ++i) {
      o[rs][i] = (f32x4){0.f, 0.f, 0.f, 0.f};
      m_r[rs][i] = -3.0e38f; l_r[rs][i] = 0.f;
    }

  for (int tk = w; tk < ntt; tk += 4) {
    const int kvb = tk * 64;
    const size_t kbase = ((size_t)b * 2048 + kvb) * 64;

    // S = Q K^T: f16 single, 2 chained MFMAs per (rs,t4)
    f32x4 sa[2][4];
#pragma unroll
    for (int t4 = 0; t4 < 4; ++t4) {
      size_t kr = kbase + (size_t)(t4 * 16 + l16) * 64 + lhi * 8;
      f16x8 kf0 = *(const f16x8*)(kb + kr);
      f16x8 kf1 = *(const f16x8*)(kb + kr + 32);
#pragma unroll
      for (int rs = 0; rs < 2; ++rs) {
        f32x4 s = (f32x4){0.f, 0.f, 0.f, 0.f};
        s = __builtin_amdgcn_mfma_f32_16x16x32_f16(aq[rs][0], kf0, s, 0, 0, 0);
        s = __builtin_amdgcn_mfma_f32_16x16x32_f16(aq[rs][1], kf1, s, 0, 0, 0);
        sa[rs][t4] = s;
      }
    }

    // V fragment loads (issued before softmax to hide latency)
    bf16x8 vv[4][2];
#pragma unroll
    for (int t4 = 0; t4 < 4; ++t4) {
      size_t vr = ((size_t)b * 64 + t4 * 16 + l16) * 2048 + kvb + lhi * 8;
      vv[t4][0] = *(const bf16x8*)(vt + vr);
      vv[t4][1] = *(const bf16x8*)(vt + vr + 32);
    }

    // causal mask: only the tile that can cross the diagonal (tk == ntt-1)
    if (tk == ntt - 1) {
#pragma unroll
      for (int rs = 0; rs < 2; ++rs) {
        int qr = j * 32 + rs * 16 + lhi * 4;
#pragma unroll
        for (int t4 = 0; t4 < 4; ++t4) {
          int col = kvb + t4 * 16 + l16;
#pragma unroll
          for (int i = 0; i < 4; ++i)
            if (col > qr + i) sa[rs][t4][i] = -1e30f;
        }
      }
    }

#pragma unroll
    for (int rs = 0; rs < 2; ++rs) {
      // online softmax
      float pf[4][4];
#pragma unroll
      for (int i = 0; i < 4; ++i) {
        float tm = fmaxf(fmaxf(sa[rs][0][i], sa[rs][1][i]), fmaxf(sa[rs][2][i], sa[rs][3][i]));
#pragma unroll
        for (int d = 1; d < 16; d <<= 1) tm = fmaxf(tm, __shfl_xor(tm, d));
        float mn = fmaxf(m_r[rs][i], tm);
        float scl = __expf(m_r[rs][i] - mn);
        float rsum = 0.f;
#pragma unroll
        for (int t4 = 0; t4 < 4; ++t4) {
          float p = __expf(sa[rs][t4][i] - mn);
          pf[t4][i] = p;
          rsum += p;
        }
#pragma unroll
        for (int d = 1; d < 16; d <<= 1) rsum += __shfl_xor(rsum, d);
        l_r[rs][i] = l_r[rs][i] * scl + rsum;
        m_r[rs][i] = mn;
#pragma unroll
        for (int t4 = 0; t4 < 4; ++t4) o[rs][t4][i] *= scl;
      }

      // P -> bf16 -> wave-private LDS (swizzled, no barrier)
      u16* pw = (u16*)p_l[w][rs];
#pragma unroll
      for (int i = 0; i < 4; ++i) {
        int rr = lhi * 4 + i;
#pragma unroll
        for (int t4 = 0; t4 < 4; ++t4) {
          int col = t4 * 16 + l16;
          pw[rr * 64 + (col ^ ((rr & 7) << 3))] = f2bf(pf[t4][i]);
        }
      }
      // PV
#pragma unroll
      for (int kk = 0; kk < 2; ++kk) {
        bf16x8 ap = lds_ld8(pw, l16, kk * 32 + lhi * 8);
#pragma unroll
        for (int t4 = 0; t4 < 4; ++t4)
          o[rs][t4] = __builtin_amdgcn_mfma_f32_16x16x32_bf16(ap, vv[t4][kk], o[rs][t4], 0, 0, 0);
      }
    }
  }

  // publish per-wave partials to LDS
#pragma unroll
  for (int rs = 0; rs < 2; ++rs)
#pragma unroll
    for (int t4 = 0; t4 < 4; ++t4) {
      int col = t4 * 16 + l16;
#pragma unroll
      for (int i = 0; i < 4; ++i)
        om[w][rs * 16 + lhi * 4 + i][col] = o[rs][t4][i];
    }
  if (l16 == 0) {
#pragma unroll
    for (int rs = 0; rs < 2; ++rs)
#pragma unroll
      for (int i = 0; i < 4; ++i) {
        int r = rs * 16 + lhi * 4 + i;
        ml[w][0][r] = m_r[rs][i];
        ml[w][1][r] = l_r[rs][i];
      }
  }
  __syncthreads();

  // in-block merge; empty waves (m=-inf, l=0) contribute exp(-inf)=0.
  {
    int r = t >> 3, c0 = (t & 7) * 8;
    float m0 = ml[0][0][r], m1 = ml[1][0][r], m2 = ml[2][0][r], m3 = ml[3][0][r];
    float M = fmaxf(fmaxf(m0, m1), fmaxf(m2, m3));
    float a0 = __expf(m0 - M), a1 = __expf(m1 - M);
    float a2 = __expf(m2 - M), a3 = __expf(m3 - M);
    float den = ml[0][1][r] * a0 + ml[1][1][r] * a1 + ml[2][1][r] * a2 + ml[3][1][r] * a3;
    float inv = 1.f / den;
    float* og = out + (qrow + r) * 64 + c0;
#pragma unroll
    for (int cc = 0; cc < 8; ++cc) {
      float v = om[0][r][c0 + cc] * a0 + om[1][r][c0 + cc] * a1 +
                om[2][r][c0 + cc] * a2 + om[3][r][c0 + cc] * a3;
      og[cc] = v * inv;
    }
  }
}

// ---------------------------------------------------------------------------
extern "C" void kernel_launch(void* const* d_in, const int* in_sizes, int n_in,
                              void* d_out, int out_size, void* d_ws, size_t ws_size,
                              hipStream_t stream) {
  const float* x  = (const float*)d_in[0];
  const float* Wk = (const float*)d_in[1];
  const float* Wq = (const float*)d_in[2];
  const float* Wv = (const float*)d_in[3];
  float* out = (float*)d_out;

  const size_t QKV = (size_t)Bc * Tc * 64;       // 1,048,576 elems
  char* w = (char*)d_ws;
  u16* kb   = (u16*)w;               w += QKV * 2;
  u16* qb   = (u16*)w;               w += QKV * 2;
  u16* vt   = (u16*)w;               w += QKV * 2;
  u16* wt_s = (u16*)w;               w += (size_t)16 * 192 * 64 * 2;

  build_wt<<<768, 256, 0, stream>>>(Wk, Wq, Wv, wt_s);
  proj_kernel<<<512, 256, 0, stream>>>(x, wt_s, kb, qb, vt);
  attn_kernel<<<512, 256, 0, stream>>>(qb, kb, vt, out);
}